// Round 10
// baseline (344.824 us; speedup 1.0000x reference)
//
#include <hip/hip_runtime.h>
#include <stdint.h>

// ExactTopKAttention: B=1, T=S=2048, H=16, E=64, topk=32, fp32.
//
// R10: two changes on the proven R9 structure:
//   (1) v_pk_fma_f32: acc as float2 ext-vectors + __builtin_elementwise_fma.
//       The 4 s-elements per row are independent chains; packing (s0,s1) and
//       (s2,s3) keeps each (t,s) chain e-sequential with identical IEEE
//       rounding -> bit-identical scores, half the VALU issue slots
//       (plain v_fma_f32 ceiling ~103 TF; pk path ~157 TF).
//   (2) TT=16 rows/block (grid 2048): halves KT L2 traffic (2->1 GB) and
//       per-FLOP addressing. acc = 64 VGPR, peak live ~95 < 128 cap from
//       __launch_bounds__(512,2) -> no spill (tripwire: WRITE_SIZE must stay
//       8 MB). Selection = two passes of 8 rows (R7 shape) with R9's
//       ballot-count threshold + rare exact bisection fallback.
//
// Carried invariants:
//   - K^T streamed from L2 (KT[h][e][s] built by transpose kernel, 8 MB ws);
//     bx&15=h pins same-h blocks to one XCD; no LDS in the GEMM.
//   - Bit-exact scores: sequential fma chain over e=0..63 per (t,s), matching
//     the np/BLAS reference rounding; *0.125f applied at decode (exact pow2).
//   - Exact top-32: threshold count in [32,64] via one 2-sigma probe (~98%)
//     else exact bisection; 64-wide bitonic on ((ord32<<32)|~idx) = value
//     desc, index asc (lax.top_k tie order); softmax over 32; V gather.

#define T_DIM 2048
#define S_DIM 2048
#define H_DIM 16
#define E_DIM 64
#define K_TOP 32
#define TT 16        // t rows per block
#define NWAVE 8

typedef float v2f __attribute__((ext_vector_type(2)));

__device__ __forceinline__ v2f pk_fma(v2f a, v2f b, v2f c) {
    return __builtin_elementwise_fma(a, b, c);
}

// order-preserving float->uint map (monotone increasing)
__device__ __forceinline__ unsigned f2ord(float f) {
    unsigned b = __float_as_uint(f);
    return (b & 0x80000000u) ? ~b : (b | 0x80000000u);
}
__device__ __forceinline__ float ord2f(unsigned u) {
    unsigned b = (u & 0x80000000u) ? (u ^ 0x80000000u) : ~u;
    return __uint_as_float(b);
}

// ---- kernel 1: K[s][h][e] -> KT[h][e][s] ----
__global__ __launch_bounds__(256)
void transpose_k(const float* __restrict__ Kg, float* __restrict__ KT) {
    __shared__ float tile[64][65];
    const int tid = threadIdx.x;
    const int h   = blockIdx.x & (H_DIM - 1);
    const int sb  = (blockIdx.x >> 4) * 64;
    #pragma unroll
    for (int sw = 0; sw < 4; sw++) {            // read 64s x 64e, coalesced on e
        int r = sw * 16 + (tid >> 4);
        int c = (tid & 15) * 4;
        float4 v = *(const float4*)(Kg + ((size_t)(sb + r) * H_DIM + h) * E_DIM + c);
        tile[r][c] = v.x; tile[r][c+1] = v.y; tile[r][c+2] = v.z; tile[r][c+3] = v.w;
    }
    __syncthreads();
    #pragma unroll
    for (int sw = 0; sw < 4; sw++) {            // write coalesced on s
        int e = sw * 16 + (tid >> 4);
        int j = (tid & 15) * 4;
        float4 v = { tile[j][e], tile[j+1][e], tile[j+2][e], tile[j+3][e] };
        *(float4*)(KT + ((size_t)h * E_DIM + e) * S_DIM + sb + j) = v;
    }
}

// ---- kernel 2: fused GEMM + exact top-32 + softmax + V ----
__global__ __launch_bounds__(512, 2)
void topk_attn_kernel(const float* __restrict__ Qg,
                      const float* __restrict__ KT,
                      const float* __restrict__ Vg,
                      float* __restrict__ Out) {
    __shared__ __align__(16) float sS[8][S_DIM];   // 64 KB scores (per pass)
    __shared__ unsigned candU[NWAVE][64];
    __shared__ int      candI[NWAVE][64];
    __shared__ unsigned wcnt[NWAVE];

    const int tid  = threadIdx.x;
    const int lane = tid & 63;
    const int wv   = tid >> 6;                 // wave 0..7
    const int bx   = blockIdx.x;
    const int h    = bx & (H_DIM - 1);         // same-h blocks -> same XCD
    const int tb   = bx >> 4;
    const int t0   = tb * TT;                  // block's first t row

    // ---- GEMM: acc2[t] = two v2f over this wave's 4 consecutive s ----
    v2f acc2[TT][2];
    #pragma unroll
    for (int t = 0; t < TT; t++) { acc2[t][0] = (v2f)(0.f); acc2[t][1] = (v2f)(0.f); }

    const int   sb  = wv * 256 + (lane << 2);  // first s of this lane
    const float* kp = KT + (size_t)h * E_DIM * S_DIM + sb;
    const float* Qb = Qg + ((size_t)t0 * H_DIM + h) * E_DIM;  // row stride 1024

    float4 k0q = *(const float4*)(kp);
    float4 k1q = *(const float4*)(kp + S_DIM);
    for (int e2 = 0; e2 < 32; e2++) {
        const int ep = (e2 + 1) & 31;          // wraps to 0 on last iter (harmless)
        float4 n0q = *(const float4*)(kp + (size_t)(2 * ep)     * S_DIM);
        float4 n1q = *(const float4*)(kp + (size_t)(2 * ep + 1) * S_DIM);
        v2f k0lo = {k0q.x, k0q.y}, k0hi = {k0q.z, k0q.w};
        v2f k1lo = {k1q.x, k1q.y}, k1hi = {k1q.z, k1q.w};
        #pragma unroll
        for (int t = 0; t < TT; t++) {
            // uniform address (blockIdx/loop-derived only) -> scalar load
            float2 qv = *(const float2*)(Qb + (size_t)t * (H_DIM * E_DIM) + 2 * e2);
            v2f qx = {qv.x, qv.x}, qy = {qv.y, qv.y};
            acc2[t][0] = pk_fma(qx, k0lo, acc2[t][0]);   // e even
            acc2[t][1] = pk_fma(qx, k0hi, acc2[t][1]);
            acc2[t][0] = pk_fma(qy, k1lo, acc2[t][0]);   // e odd
            acc2[t][1] = pk_fma(qy, k1hi, acc2[t][1]);
        }
        k0q = n0q; k1q = n1q;
    }

    // ---- selection: 2 passes x 8 rows; wave wv owns local row wv ----
    const float* Vb = Vg + (size_t)h * E_DIM;

    for (int p = 0; p < 2; p++) {
        __syncthreads();                       // prior pass reads done
        #pragma unroll
        for (int r = 0; r < 8; r++) {
            int rr = p * 8 + r;
            float4 f4 = { acc2[rr][0].x, acc2[rr][0].y,
                          acc2[rr][1].x, acc2[rr][1].y };
            *(float4*)(&sS[r][sb]) = f4;
        }
        __syncthreads();

        // wave wv reads full row wv: 32 vals/lane, s = i*64+lane (2-way free)
        unsigned u[32];
        #pragma unroll
        for (int i = 0; i < 32; i++) u[i] = f2ord(sS[wv][i * 64 + lane]);

        // --- threshold: one 2-sigma probe; rare exact bisection fallback ---
        auto wave_count = [&](unsigned t) -> int {   // wave-uniform result
            int c = 0;
            #pragma unroll
            for (int i = 0; i < 32; i++)
                c += __popcll(__ballot(u[i] >= t));
            return c;
        };

        unsigned thr = 0xC1800000u;            // f2ord(16.0f) = 2sigma pre-scale
        int c = wave_count(thr);
        if (c < K_TOP || c > 64) {             // ~2% of rows
            unsigned lo = (c >= K_TOP) ? thr : 0u;          // f(lo) >= 32
            unsigned hi = (c >= K_TOP) ? 0xFFFFFFFFu : thr; // f(hi) <  32
            bool found = false;
            while (!found && (hi - lo > 1u)) {
                unsigned mid = lo + ((hi - lo) >> 1);
                int cm = wave_count(mid);
                if (cm >= K_TOP && cm <= 64) { thr = mid; c = cm; found = true; }
                else if (cm >= K_TOP) lo = mid;
                else hi = mid;
            }
            if (!found) { thr = lo; c = wave_count(lo); }  // exact v32 (dupe clamp)
        }
        int n = (c > 64) ? 64 : c;

        // --- collect candidates with u >= thr ---
        if (lane == 0) wcnt[wv] = 0u;
        #pragma unroll
        for (int i = 0; i < 32; i++) {
            if (u[i] >= thr) {
                unsigned pos = atomicAdd(&wcnt[wv], 1u);
                if (pos < 64u) {
                    candU[wv][pos] = u[i];
                    candI[wv][pos] = i * 64 + lane;
                }
            }
        }

        // --- 64-wide bitonic, descending by (value, then lower index) ---
        unsigned long long key = 0ull;
        if (lane < n)
            key = (((unsigned long long)candU[wv][lane]) << 32)
                | (unsigned)(~candI[wv][lane]);
        #pragma unroll
        for (int k = 2; k <= 64; k <<= 1)
            #pragma unroll
            for (int j = k >> 1; j > 0; j >>= 1) {
                unsigned long long ok = __shfl_xor(key, j);
                bool takemax = ((lane & j) == 0) ^ ((lane & k) != 0);
                bool mineG   = key > ok;
                key = (takemax == mineG) ? key : ok;
            }

        // --- decode (exact pow2 scale), softmax, V gather, store ---
        float val  = ord2f((unsigned)(key >> 32)) * 0.125f;
        int   sidx = (int)(~(unsigned)key);
        float m = __shfl(val, 0);              // lane 0 = max (n >= 32 always)
        float w = (lane < K_TOP) ? expf(val - m) : 0.f;
        float Z = w;
        #pragma unroll
        for (int d = 32; d > 0; d >>= 1) Z += __shfl_xor(Z, d);
        float pr = w / Z;

        float o = 0.f;
        #pragma unroll
        for (int i2 = 0; i2 < K_TOP; i2++) {
            float pi = __shfl(pr, i2);
            int   s2 = __shfl(sidx, i2);
            o = fmaf(pi, Vb[(size_t)s2 * (H_DIM * E_DIM) + lane], o);
        }
        int t = t0 + p * 8 + wv;
        Out[((size_t)t * H_DIM + h) * E_DIM + lane] = o;
    }
}

extern "C" void kernel_launch(void* const* d_in, const int* in_sizes, int n_in,
                              void* d_out, int out_size, void* d_ws, size_t ws_size,
                              hipStream_t stream) {
    const float* Q = (const float*)d_in[0];
    const float* K = (const float*)d_in[1];
    const float* V = (const float*)d_in[2];
    float* O  = (float*)d_out;
    float* KT = (float*)d_ws;                  // 16*64*2048*4 = 8 MB
    (void)in_sizes; (void)n_in; (void)out_size; (void)ws_size;
    transpose_k<<<dim3(H_DIM * (S_DIM / 64)), dim3(256), 0, stream>>>(K, KT);
    topk_attn_kernel<<<dim3((T_DIM / TT) * H_DIM), dim3(512), 0, stream>>>(Q, KT, V, O);
}

// Round 11
// 231.950 us; speedup vs baseline: 1.4866x; 1.4866x over previous
//
#include <hip/hip_runtime.h>
#include <stdint.h>

// ExactTopKAttention: B=1, T=S=2048, H=16, E=64, topk=32, fp32.
//
// R11 = R9 (proven: VGPR=52, zero scratch, 195us kernel) + v_pk_fma_f32 ONLY.
// R10's TT=16 re-triggered accumulator spill (VGPR_Count=64, WRITE 418MB) --
// the allocator's occupancy heuristic overrides launch_bounds caps, so the
// live set must stay ~<=64 regs at 512 threads. TT stays 8.
//   pk packing: the 4 s-elements per (row,lane) are INDEPENDENT chains;
//   packing (s0,s1),(s2,s3) keeps each (t,s) chain e-sequential with
//   identical IEEE rounding -> bit-identical scores, half the VALU issue
//   (plain v_fma_f32 ~103 TF ceiling; packed ~157 TF).
//
// Carried invariants (R8/R9):
//   kernel 1: transpose K per head -> KT[h][e][s] in d_ws (8 MB).
//   kernel 2: block = (h, 8 t-rows), 512 thr = 8 waves; wave owns a 256-wide
//     s-slice of all 8 rows; acc2[8][2] v2f = 32 VGPRs. Per e-pair: 2
//     coalesced float4 KT loads (L2-resident per head; bx&15=h pins same-h
//     blocks to one XCD) + Q uniform scalar loads. No LDS in the GEMM.
//   Bit-exact scores: sequential fma chain over e=0..63 per (t,s) (matches
//     np/BLAS reference rounding); *0.125f applied at decode (exact pow2).
//   selection: scores -> LDS sS[8][2048] (conflict-free), wave = row, 32
//     vals/lane stride-64; threshold = one 2-sigma ballot-count probe (~98%
//     of rows in [32,64]) else exact bisection on ordered bits; collect via
//     tiny per-wave atomic append; 64-wide bitonic on ((ord32<<32)|~idx)
//     (value desc, index asc = lax.top_k tie order); softmax; V gather.

#define T_DIM 2048
#define S_DIM 2048
#define H_DIM 16
#define E_DIM 64
#define K_TOP 32
#define TT 8         // t rows per block
#define NWAVE 8

typedef float v2f __attribute__((ext_vector_type(2)));

__device__ __forceinline__ v2f pk_fma(v2f a, v2f b, v2f c) {
    return __builtin_elementwise_fma(a, b, c);
}

// order-preserving float->uint map (monotone increasing)
__device__ __forceinline__ unsigned f2ord(float f) {
    unsigned b = __float_as_uint(f);
    return (b & 0x80000000u) ? ~b : (b | 0x80000000u);
}
__device__ __forceinline__ float ord2f(unsigned u) {
    unsigned b = (u & 0x80000000u) ? (u ^ 0x80000000u) : ~u;
    return __uint_as_float(b);
}

// ---- kernel 1: K[s][h][e] -> KT[h][e][s] ----
__global__ __launch_bounds__(256)
void transpose_k(const float* __restrict__ Kg, float* __restrict__ KT) {
    __shared__ float tile[64][65];
    const int tid = threadIdx.x;
    const int h   = blockIdx.x & (H_DIM - 1);
    const int sb  = (blockIdx.x >> 4) * 64;
    #pragma unroll
    for (int sw = 0; sw < 4; sw++) {            // read 64s x 64e, coalesced on e
        int r = sw * 16 + (tid >> 4);
        int c = (tid & 15) * 4;
        float4 v = *(const float4*)(Kg + ((size_t)(sb + r) * H_DIM + h) * E_DIM + c);
        tile[r][c] = v.x; tile[r][c+1] = v.y; tile[r][c+2] = v.z; tile[r][c+3] = v.w;
    }
    __syncthreads();
    #pragma unroll
    for (int sw = 0; sw < 4; sw++) {            // write coalesced on s
        int e = sw * 16 + (tid >> 4);
        int j = (tid & 15) * 4;
        float4 v = { tile[j][e], tile[j+1][e], tile[j+2][e], tile[j+3][e] };
        *(float4*)(KT + ((size_t)h * E_DIM + e) * S_DIM + sb + j) = v;
    }
}

// ---- kernel 2: fused GEMM + exact top-32 + softmax + V ----
__global__ __launch_bounds__(512, 2)
void topk_attn_kernel(const float* __restrict__ Qg,
                      const float* __restrict__ KT,
                      const float* __restrict__ Vg,
                      float* __restrict__ Out) {
    __shared__ __align__(16) float sS[TT][S_DIM];   // 64 KB scores
    __shared__ unsigned candU[NWAVE][64];
    __shared__ int      candI[NWAVE][64];
    __shared__ unsigned wcnt[NWAVE];

    const int tid  = threadIdx.x;
    const int lane = tid & 63;
    const int wv   = tid >> 6;                 // wave 0..7
    const int bx   = blockIdx.x;
    const int h    = bx & (H_DIM - 1);         // same-h blocks -> same XCD
    const int tb   = bx >> 4;
    const int t0   = tb * TT;                  // block's first t row

    // ---- GEMM: acc2[t] = two v2f over this wave's 4 consecutive s ----
    v2f acc2[TT][2];
    #pragma unroll
    for (int t = 0; t < TT; t++) { acc2[t][0] = (v2f)(0.f); acc2[t][1] = (v2f)(0.f); }

    const int   sb  = wv * 256 + (lane << 2);  // first s of this lane
    const float* kp = KT + (size_t)h * E_DIM * S_DIM + sb;
    const float* Qb = Qg + ((size_t)t0 * H_DIM + h) * E_DIM;  // row stride 1024

    float4 k0q = *(const float4*)(kp);
    float4 k1q = *(const float4*)(kp + S_DIM);
    for (int e2 = 0; e2 < 32; e2++) {
        const int ep = (e2 + 1) & 31;          // wraps to 0 on last iter (harmless)
        float4 n0q = *(const float4*)(kp + (size_t)(2 * ep)     * S_DIM);
        float4 n1q = *(const float4*)(kp + (size_t)(2 * ep + 1) * S_DIM);
        v2f k0lo = {k0q.x, k0q.y}, k0hi = {k0q.z, k0q.w};
        v2f k1lo = {k1q.x, k1q.y}, k1hi = {k1q.z, k1q.w};
        #pragma unroll
        for (int t = 0; t < TT; t++) {
            // uniform address (blockIdx/loop-derived only) -> scalar load
            float2 qv = *(const float2*)(Qb + (size_t)t * (H_DIM * E_DIM) + 2 * e2);
            v2f qx = {qv.x, qv.x}, qy = {qv.y, qv.y};
            acc2[t][0] = pk_fma(qx, k0lo, acc2[t][0]);   // e even
            acc2[t][1] = pk_fma(qx, k0hi, acc2[t][1]);
            acc2[t][0] = pk_fma(qy, k1lo, acc2[t][0]);   // e odd
            acc2[t][1] = pk_fma(qy, k1hi, acc2[t][1]);
        }
        k0q = n0q; k1q = n1q;
    }

    // ---- LDS transpose: waves<->rows; then selection is wave-local ----
    #pragma unroll
    for (int r = 0; r < TT; r++) {
        float4 f4 = { acc2[r][0].x, acc2[r][0].y, acc2[r][1].x, acc2[r][1].y };
        *(float4*)(&sS[r][sb]) = f4;
    }
    __syncthreads();

    // wave wv owns row wv: 32 vals/lane, s = i*64+lane (2-way = free)
    unsigned u[32];
    #pragma unroll
    for (int i = 0; i < 32; i++) u[i] = f2ord(sS[wv][i * 64 + lane]);

    // --- threshold: one fixed-probe count, rare exact bisection fallback ---
    auto wave_count = [&](unsigned t) -> int {   // wave-uniform result
        int c = 0;
        #pragma unroll
        for (int i = 0; i < 32; i++)
            c += __popcll(__ballot(u[i] >= t));
        return c;
    };

    unsigned thr = 0xC1800000u;                // f2ord(16.0f) = 2sigma pre-scale
    int c = wave_count(thr);
    if (c < K_TOP || c > 64) {                 // ~2% of rows
        // invariant: f(lo) >= 32 (f(0)=2048), f(hi) < 32 (f(UINT_MAX)~0)
        unsigned lo = (c >= K_TOP) ? thr : 0u;
        unsigned hi = (c >= K_TOP) ? 0xFFFFFFFFu : thr;
        bool found = false;
        while (!found && (hi - lo > 1u)) {
            unsigned mid = lo + ((hi - lo) >> 1);
            int cm = wave_count(mid);
            if (cm >= K_TOP && cm <= 64) { thr = mid; c = cm; found = true; }
            else if (cm >= K_TOP) lo = mid;
            else hi = mid;
        }
        if (!found) { thr = lo; c = wave_count(lo); }  // exact v32 (dupes clamp)
    }
    int n = (c > 64) ? 64 : c;                 // pathological-duplicate clamp

    // --- collect candidates with u >= thr (tiny per-wave atomic append) ---
    if (lane == 0) wcnt[wv] = 0u;
    #pragma unroll
    for (int i = 0; i < 32; i++) {
        if (u[i] >= thr) {
            unsigned pos = atomicAdd(&wcnt[wv], 1u);
            if (pos < 64u) {
                candU[wv][pos] = u[i];
                candI[wv][pos] = i * 64 + lane;
            }
        }
    }

    // --- 64-wide bitonic, descending by (value, then lower index) ---
    unsigned long long key = 0ull;
    if (lane < n)
        key = (((unsigned long long)candU[wv][lane]) << 32)
            | (unsigned)(~candI[wv][lane]);
    #pragma unroll
    for (int k = 2; k <= 64; k <<= 1)
        #pragma unroll
        for (int j = k >> 1; j > 0; j >>= 1) {
            unsigned long long ok = __shfl_xor(key, j);
            bool takemax = ((lane & j) == 0) ^ ((lane & k) != 0);
            bool mineG   = key > ok;
            key = (takemax == mineG) ? key : ok;
        }

    // --- decode (apply exact pow2 scale now), softmax, V gather, store ---
    const float* Vb = Vg + (size_t)h * E_DIM;
    float val  = ord2f((unsigned)(key >> 32)) * 0.125f;
    int   sidx = (int)(~(unsigned)key);
    float m = __shfl(val, 0);                  // lane 0 = max (n >= 32 always)
    float w = (lane < K_TOP) ? expf(val - m) : 0.f;
    float Z = w;
    #pragma unroll
    for (int d = 32; d > 0; d >>= 1) Z += __shfl_xor(Z, d);
    float pr = w / Z;

    float o = 0.f;
    #pragma unroll
    for (int i2 = 0; i2 < K_TOP; i2++) {
        float pi = __shfl(pr, i2);
        int   s2 = __shfl(sidx, i2);
        o = fmaf(pi, Vb[(size_t)s2 * (H_DIM * E_DIM) + lane], o);
    }
    int t = t0 + wv;
    Out[((size_t)t * H_DIM + h) * E_DIM + lane] = o;
}

extern "C" void kernel_launch(void* const* d_in, const int* in_sizes, int n_in,
                              void* d_out, int out_size, void* d_ws, size_t ws_size,
                              hipStream_t stream) {
    const float* Q = (const float*)d_in[0];
    const float* K = (const float*)d_in[1];
    const float* V = (const float*)d_in[2];
    float* O  = (float*)d_out;
    float* KT = (float*)d_ws;                  // 16*64*2048*4 = 8 MB
    (void)in_sizes; (void)n_in; (void)out_size; (void)ws_size;
    transpose_k<<<dim3(H_DIM * (S_DIM / 64)), dim3(256), 0, stream>>>(K, KT);
    topk_attn_kernel<<<dim3((T_DIM / TT) * H_DIM), dim3(512), 0, stream>>>(Q, KT, V, O);
}

// Round 12
// 219.343 us; speedup vs baseline: 1.5721x; 1.0575x over previous
//
#include <hip/hip_runtime.h>
#include <stdint.h>

// ExactTopKAttention: B=1, T=S=2048, H=16, E=64, topk=32, fp32.
//
// R12: occupancy push. R11 sits at 190us with VALU busy ~116us and 37%
// occupancy -- LDS (70KB: fp32 score buffer) caps 2 blocks/CU. Change:
//   - LDS scores stored as u16 = ord32>>16 (32 KB instead of 64 KB).
//   - threshold found on the 16-bit domain (count16(t)==count32(t<<16),
//     exact at bin granularity; 2-sigma probe, rare exact bisection).
//   - candidates collected with EXACT u32 values from the accumulator
//     registers (slice-owner waves), per-row atomic append lists; full
//     32-bit sort keeps top-32 exact (superset argument as before).
//   LDS ~36.9 KB -> 4 blocks/CU (32 waves), occupancy 37 -> ~70%.
//
// Carried invariants (R8-R11):
//   kernel 1: transpose K per head -> KT[h][e][s] in d_ws (8 MB).
//   kernel 2: block = (h, 8 t-rows), 512 thr = 8 waves; wave owns a 256-wide
//     s-slice of all 8 rows; acc2[8][2] v2f = 32 VGPRs; per e-pair 2
//     coalesced float4 KT loads (L2-resident per head; bx&15=h pins same-h
//     blocks to one XCD) + Q uniform scalar loads; no LDS in the GEMM.
//   Bit-exact scores: sequential fma chain over e=0..63 per (t,s) (packed
//     pairs are independent s-chains; matches np/BLAS reference rounding);
//     *0.125f applied at decode (exact pow2).
//   Exact top-32: 64-wide bitonic on ((ord32<<32)|~idx) = value desc, index
//     asc (lax.top_k tie order); softmax over 32; V gather; store.

#define T_DIM 2048
#define S_DIM 2048
#define H_DIM 16
#define E_DIM 64
#define K_TOP 32
#define TT 8         // t rows per block
#define NWAVE 8

typedef float v2f __attribute__((ext_vector_type(2)));

__device__ __forceinline__ v2f pk_fma(v2f a, v2f b, v2f c) {
    return __builtin_elementwise_fma(a, b, c);
}

// order-preserving float->uint map (monotone increasing)
__device__ __forceinline__ unsigned f2ord(float f) {
    unsigned b = __float_as_uint(f);
    return (b & 0x80000000u) ? ~b : (b | 0x80000000u);
}
__device__ __forceinline__ float ord2f(unsigned u) {
    unsigned b = (u & 0x80000000u) ? (u ^ 0x80000000u) : ~u;
    return __uint_as_float(b);
}

// ---- kernel 1: K[s][h][e] -> KT[h][e][s] ----
__global__ __launch_bounds__(256)
void transpose_k(const float* __restrict__ Kg, float* __restrict__ KT) {
    __shared__ float tile[64][65];
    const int tid = threadIdx.x;
    const int h   = blockIdx.x & (H_DIM - 1);
    const int sb  = (blockIdx.x >> 4) * 64;
    #pragma unroll
    for (int sw = 0; sw < 4; sw++) {            // read 64s x 64e, coalesced on e
        int r = sw * 16 + (tid >> 4);
        int c = (tid & 15) * 4;
        float4 v = *(const float4*)(Kg + ((size_t)(sb + r) * H_DIM + h) * E_DIM + c);
        tile[r][c] = v.x; tile[r][c+1] = v.y; tile[r][c+2] = v.z; tile[r][c+3] = v.w;
    }
    __syncthreads();
    #pragma unroll
    for (int sw = 0; sw < 4; sw++) {            // write coalesced on s
        int e = sw * 16 + (tid >> 4);
        int j = (tid & 15) * 4;
        float4 v = { tile[j][e], tile[j+1][e], tile[j+2][e], tile[j+3][e] };
        *(float4*)(KT + ((size_t)h * E_DIM + e) * S_DIM + sb + j) = v;
    }
}

// ---- kernel 2: fused GEMM + exact top-32 + softmax + V ----
__global__ __launch_bounds__(512, 2)
void topk_attn_kernel(const float* __restrict__ Qg,
                      const float* __restrict__ KT,
                      const float* __restrict__ Vg,
                      float* __restrict__ Out) {
    __shared__ __align__(16) unsigned short sU[TT][S_DIM];  // 32 KB u16 keys
    __shared__ unsigned candU[TT][64];
    __shared__ int      candI[TT][64];
    __shared__ unsigned wcnt[TT];
    __shared__ unsigned thrA[TT];

    const int tid  = threadIdx.x;
    const int lane = tid & 63;
    const int wv   = tid >> 6;                 // wave 0..7
    const int bx   = blockIdx.x;
    const int h    = bx & (H_DIM - 1);         // same-h blocks -> same XCD
    const int tb   = bx >> 4;
    const int t0   = tb * TT;                  // block's first t row

    // ---- GEMM: acc2[t] = two v2f over this wave's 4 consecutive s ----
    v2f acc2[TT][2];
    #pragma unroll
    for (int t = 0; t < TT; t++) { acc2[t][0] = (v2f)(0.f); acc2[t][1] = (v2f)(0.f); }

    const int   sb  = wv * 256 + (lane << 2);  // first s of this lane
    const float* kp = KT + (size_t)h * E_DIM * S_DIM + sb;
    const float* Qb = Qg + ((size_t)t0 * H_DIM + h) * E_DIM;  // row stride 1024

    float4 k0q = *(const float4*)(kp);
    float4 k1q = *(const float4*)(kp + S_DIM);
    for (int e2 = 0; e2 < 32; e2++) {
        const int ep = (e2 + 1) & 31;          // wraps to 0 on last iter (harmless)
        float4 n0q = *(const float4*)(kp + (size_t)(2 * ep)     * S_DIM);
        float4 n1q = *(const float4*)(kp + (size_t)(2 * ep + 1) * S_DIM);
        v2f k0lo = {k0q.x, k0q.y}, k0hi = {k0q.z, k0q.w};
        v2f k1lo = {k1q.x, k1q.y}, k1hi = {k1q.z, k1q.w};
        #pragma unroll
        for (int t = 0; t < TT; t++) {
            // uniform address (blockIdx/loop-derived only) -> scalar load
            float2 qv = *(const float2*)(Qb + (size_t)t * (H_DIM * E_DIM) + 2 * e2);
            v2f qx = {qv.x, qv.x}, qy = {qv.y, qv.y};
            acc2[t][0] = pk_fma(qx, k0lo, acc2[t][0]);   // e even
            acc2[t][1] = pk_fma(qx, k0hi, acc2[t][1]);
            acc2[t][0] = pk_fma(qy, k1lo, acc2[t][0]);   // e odd
            acc2[t][1] = pk_fma(qy, k1hi, acc2[t][1]);
        }
        k0q = n0q; k1q = n1q;
    }

    // ---- write u16 ordered keys to LDS (acc2 stays live for collect) ----
    #pragma unroll
    for (int r = 0; r < TT; r++) {
        unsigned a = f2ord(acc2[r][0].x) >> 16;
        unsigned b = f2ord(acc2[r][0].y) >> 16;
        unsigned c = f2ord(acc2[r][1].x) >> 16;
        unsigned d = f2ord(acc2[r][1].y) >> 16;
        uint2 pk; pk.x = a | (b << 16); pk.y = c | (d << 16);
        *(uint2*)(&sU[r][sb]) = pk;
    }
    if (lane == 0) wcnt[wv] = 0u;
    __syncthreads();

    // ---- threshold find: wave wv owns row wv, 16-bit domain ----
    unsigned pk16[16];                         // packed u16 pairs of row wv
    {
        const unsigned* rowp = (const unsigned*)(&sU[wv][0]);
        #pragma unroll
        for (int j = 0; j < 16; j++) pk16[j] = rowp[j * 64 + lane];
    }
    auto count16 = [&](unsigned t) -> int {    // wave-uniform result
        int c = 0;
        #pragma unroll
        for (int j = 0; j < 16; j++) {
            c += __popcll(__ballot((pk16[j] & 0xFFFFu) >= t));
            c += __popcll(__ballot((pk16[j] >> 16) >= t));
        }
        return c;
    };

    unsigned thr = 0xC180u;                    // f2ord(16.0f)>>16 (2sigma)
    int c = count16(thr);
    if (c < K_TOP || c > 64) {                 // ~2% of rows
        // invariant: count(lo) >= 32 (count(0)=2048), count(hi) < 32
        unsigned lo = (c >= K_TOP) ? thr : 0u;
        unsigned hi = (c >= K_TOP) ? 0x10000u : thr;
        bool found = false;
        while (!found && (hi - lo > 1u)) {
            unsigned mid = lo + ((hi - lo) >> 1);
            int cm = count16(mid);
            if (cm >= K_TOP && cm <= 64) { thr = mid; c = cm; found = true; }
            else if (cm >= K_TOP) lo = mid;
            else hi = mid;
        }
        if (!found) { thr = lo; c = count16(lo); }  // bin-tie clamp (rare)
    }
    if (lane == 0) thrA[wv] = thr;
    __syncthreads();

    // ---- collect: every wave appends its register-exact candidates ----
    #pragma unroll
    for (int r = 0; r < TT; r++) {
        unsigned tr = thrA[r];                 // same-address broadcast read
        unsigned uu0 = f2ord(acc2[r][0].x);
        unsigned uu1 = f2ord(acc2[r][0].y);
        unsigned uu2 = f2ord(acc2[r][1].x);
        unsigned uu3 = f2ord(acc2[r][1].y);
        unsigned uu[4] = {uu0, uu1, uu2, uu3};
        #pragma unroll
        for (int q = 0; q < 4; q++) {
            if ((uu[q] >> 16) >= tr) {
                unsigned pos = atomicAdd(&wcnt[r], 1u);
                if (pos < 64u) {
                    candU[r][pos] = uu[q];
                    candI[r][pos] = sb + q;
                }
            }
        }
    }
    __syncthreads();

    // ---- wave wv: bitonic + softmax + V gather for row wv ----
    unsigned nw = wcnt[wv];
    int n = (nw > 64u) ? 64 : (int)nw;         // pathological-tie clamp

    unsigned long long key = 0ull;
    if (lane < n)
        key = (((unsigned long long)candU[wv][lane]) << 32)
            | (unsigned)(~candI[wv][lane]);
    #pragma unroll
    for (int k = 2; k <= 64; k <<= 1)
        #pragma unroll
        for (int j = k >> 1; j > 0; j >>= 1) {
            unsigned long long ok = __shfl_xor(key, j);
            bool takemax = ((lane & j) == 0) ^ ((lane & k) != 0);
            bool mineG   = key > ok;
            key = (takemax == mineG) ? key : ok;
        }

    // --- decode (apply exact pow2 scale now), softmax, V gather, store ---
    const float* Vb = Vg + (size_t)h * E_DIM;
    float val  = ord2f((unsigned)(key >> 32)) * 0.125f;
    int   sidx = (int)(~(unsigned)key);
    float m = __shfl(val, 0);                  // lane 0 = max (n >= 32 always)
    float w = (lane < K_TOP) ? expf(val - m) : 0.f;
    float Z = w;
    #pragma unroll
    for (int d = 32; d > 0; d >>= 1) Z += __shfl_xor(Z, d);
    float pr = w / Z;

    float o = 0.f;
    #pragma unroll
    for (int i2 = 0; i2 < K_TOP; i2++) {
        float pi = __shfl(pr, i2);
        int   s2 = __shfl(sidx, i2);
        o = fmaf(pi, Vb[(size_t)s2 * (H_DIM * E_DIM) + lane], o);
    }
    int t = t0 + wv;
    Out[((size_t)t * H_DIM + h) * E_DIM + lane] = o;
}

extern "C" void kernel_launch(void* const* d_in, const int* in_sizes, int n_in,
                              void* d_out, int out_size, void* d_ws, size_t ws_size,
                              hipStream_t stream) {
    const float* Q = (const float*)d_in[0];
    const float* K = (const float*)d_in[1];
    const float* V = (const float*)d_in[2];
    float* O  = (float*)d_out;
    float* KT = (float*)d_ws;                  // 16*64*2048*4 = 8 MB
    (void)in_sizes; (void)n_in; (void)out_size; (void)ws_size;
    transpose_k<<<dim3(H_DIM * (S_DIM / 64)), dim3(256), 0, stream>>>(K, KT);
    topk_attn_kernel<<<dim3((T_DIM / TT) * H_DIM), dim3(512), 0, stream>>>(Q, KT, V, O);
}